// Round 18
// baseline (244.838 us; speedup 1.0000x reference)
//
#include <hip/hip_runtime.h>
#include <stdint.h>

#define BB 8
#define CC 256
#define KK 19
#define HWN 65536
#define H1 2048
#define H2 512
#define NC 38
#define NEG 0.2f
#define NSL 8               // hw slices (1024 blocks = exactly 4/CU resident)
#define HWS (HWN / NSL)     // 8192 hw per slice
#define HWT 256             // hw per chunk
#define NCH (HWS / HWT)     // 32 chunks per slice
#define CAMF4 (KK * HWT / 4)   // 1216 float4 per cam chunk
#define NROW (BB * KK)      // 152

typedef float nat4 __attribute__((ext_vector_type(4)));   // native vec for nt builtins

// async global->LDS, 16 B per lane (wave-uniform LDS base + lane*16)
__device__ __forceinline__ void gload_lds16(const float4* g, float4* l) {
    __builtin_amdgcn_global_load_lds(
        (const __attribute__((address_space(1))) void*)g,
        (__attribute__((address_space(3))) void*)l, 16, 0, 0);
}

// ---------------- Stage 1: partial[sl][b][k][c] = sum_{hw in slice} cam*x ----------------
// R18 = R17 (234us) + single-generation occupancy: NSL=8 -> 1024 blocks =
// exactly 4 blocks/CU (4 x 38.9 KB = 155.6 <= 160 KB LDS), ALL resident for
// one 32-chunk pass. Removes the generation boundary (pipeline refill +
// vmcnt drain between the two 4-block waves of the old 2048-block grid).
// Keeps: dbuf + async gload_lds staging, nt x-loads, gt-skip (R17: -26us,
// proved issue-bound component).
__global__ __launch_bounds__(256) void k_feat(const float* __restrict__ x,
                                              const float* __restrict__ cam,
                                              const int* __restrict__ gt,
                                              float* __restrict__ partial) {
    __shared__ float cams[2][KK * HWT];      // 2 x 19456 B
    const int b  = blockIdx.y;
    const int cg = blockIdx.x & 15;          // channel group of 16
    const int sl = blockIdx.x >> 4;          // hw slice 0..7
    const int t  = threadIdx.x;
    const int w  = t >> 6;                   // wave 0..3
    const int l  = t & 63;                   // lane
    const int c0 = cg * 16 + w * 4;

    // active-row bitmask (block-uniform -> scalar loads/branches)
    unsigned gtm = 0;
#pragma unroll
    for (int k = 0; k < KK; ++k)
        gtm |= (gt[b * KK + k] > 0) ? (1u << k) : 0u;

    const nat4*  __restrict__ x4  = reinterpret_cast<const nat4*>(x);
    const float4* __restrict__ cb4 = reinterpret_cast<const float4*>(cam) + (size_t)b * KK * (HWN / 4);
    const int slbase = sl * (HWS / 4);

    float acc[KK][4];
#pragma unroll
    for (int k = 0; k < KK; ++k)
#pragma unroll
        for (int c = 0; c < 4; ++c) acc[k][c] = 0.f;

    // stage cam chunk ch into buf via async global->LDS; skip masked rows
    auto stage = [&](int buf, int ch) {
        const int f0 = slbase + ch * (HWT / 4);
#pragma unroll
        for (int j = 0; j < 5; ++j) {
            const int idx = w * 64 + j * 256;            // wave-uniform f4 base
            const int row = idx >> 6;                    // cam row (k)
            if (idx < CAMF4 && ((gtm >> row) & 1)) {     // wave-uniform guard
                gload_lds16(cb4 + (size_t)row * (HWN / 4) + f0 + l,
                            ((float4*)cams[buf]) + idx + l);
            }
        }
    };
    auto loadx = [&](nat4 (&xv)[4], int ch) {
        const int f0 = slbase + ch * (HWT / 4);
#pragma unroll
        for (int c = 0; c < 4; ++c)
            xv[c] = __builtin_nontemporal_load(
                x4 + (size_t)(b * CC + c0 + c) * (HWN / 4) + f0 + l);
    };
    auto consume = [&](int buf, const nat4 (&xv)[4]) {
        const float4* cs = (const float4*)cams[buf];
#pragma unroll
        for (int k = 0; k < KK; ++k) {
            if ((gtm >> k) & 1) {                        // uniform skip
                const float4 cv = cs[k * (HWT / 4) + l]; // conflict-free b128
#pragma unroll
                for (int c = 0; c < 4; ++c)
                    acc[k][c] = fmaf(xv[c].w, cv.w, fmaf(xv[c].z, cv.z,
                                fmaf(xv[c].y, cv.y, fmaf(xv[c].x, cv.x, acc[k][c]))));
            }
        }
    };

    nat4 xa[4], xb[4];
    loadx(xa, 0);
    stage(0, 0);
    __syncthreads();                                     // prologue drain

#pragma unroll 1
    for (int ch = 0; ch < NCH; ch += 2) {
        loadx(xb, ch + 1);                               // prefetch chunk ch+1
        stage(1, ch + 1);
        consume(0, xa);                                  // compute hides latency
        __syncthreads();
        if (ch + 2 < NCH) { loadx(xa, ch + 2); stage(0, ch + 2); }
        consume(1, xb);
        __syncthreads();
    }

    // butterfly wave-reduce each (k,c); lane 0 stores per-slice partial
    // (masked k: acc stayed 0 -> stores 0 -> finite & unused downstream)
#pragma unroll
    for (int k = 0; k < KK; ++k) {
#pragma unroll
        for (int c = 0; c < 4; ++c) {
            float v = acc[k][c];
#pragma unroll
            for (int off = 32; off; off >>= 1) v += __shfl_xor(v, off, 64);
            if (l == 0)
                __builtin_nontemporal_store(v,
                    partial + (size_t)sl * (NROW * CC) +
                    (size_t)(b * KK + k) * CC + c0 + c);
        }
    }
}

// ---------------- Stage 2a (fused reduce): h1 = lrelu(feat @ W1 + b1) ----------------
// grid (8, 152), block 256, ONE row per block; masked rows return early
// (their h1 is never read: k_mlp2p skips them too). Block (0,0) zeroes scal
// BEFORE the mask check.
__global__ __launch_bounds__(256) void k_mlp1(const float* __restrict__ partial,
                                              const float* __restrict__ W1,
                                              const float* __restrict__ b1,
                                              const int* __restrict__ gt,
                                              float* __restrict__ h1,
                                              float* __restrict__ scal) {
    __shared__ float fr[CC];
    const int r = blockIdx.y;                 // 0..151
    const int t = threadIdx.x;
    if (blockIdx.x == 0 && blockIdx.y == 0 && t < 16) scal[t] = 0.f;
    if (gt[r] <= 0) return;                   // masked row: skip entirely

    float s0 = 0.f;
#pragma unroll
    for (int slc = 0; slc < NSL; ++slc)
        s0 += partial[((size_t)slc * NROW + r) * CC + t];
    fr[t] = s0 * (1.0f / (float)HWN);
    __syncthreads();

    const int j = blockIdx.x * 256 + t;
    const float4* f0 = (const float4*)fr;
    float a0 = b1[j];
#pragma unroll 8
    for (int c4 = 0; c4 < CC / 4; ++c4) {
        const float4 v0 = f0[c4];
        const size_t cb = (size_t)(c4 * 4) * H1 + j;
        a0 = fmaf(v0.x, W1[cb], a0);
        a0 = fmaf(v0.y, W1[cb + H1], a0);
        a0 = fmaf(v0.z, W1[cb + 2 * H1], a0);
        a0 = fmaf(v0.w, W1[cb + 3 * H1], a0);
    }
    h1[(size_t)r * H1 + j] = a0 > 0.f ? a0 : NEG * a0;
}

// ---------------- Stage 2b: c-split partial GEMM for h2 (no bias) ----------------
// grid (4 jtile, 152 row, 4 cslice), block 128; masked rows return early
// (their part2 entries stay garbage-but-finite; k_loss multiplies by mask).
__global__ __launch_bounds__(128) void k_mlp2p(const float* __restrict__ h1,
                                               const float* __restrict__ W2,
                                               const int* __restrict__ gt,
                                               float* __restrict__ part) {
    const int r = blockIdx.y;
    if (gt[r] <= 0) return;                   // masked row: skip
    const int j  = blockIdx.x * 128 + threadIdx.x;
    const int cb = blockIdx.z * 512;
    const float4* __restrict__ f0 = reinterpret_cast<const float4*>(h1 + (size_t)r * H1 + cb);

    float a0 = 0.f;
#pragma unroll 8
    for (int c4 = 0; c4 < 128; ++c4) {
        const float4 v0 = f0[c4];
        const size_t wb = (size_t)(cb + c4 * 4) * H2 + j;
        a0 = fmaf(v0.x, W2[wb], a0);
        a0 = fmaf(v0.y, W2[wb + H2], a0);
        a0 = fmaf(v0.z, W2[wb + 2 * H2], a0);
        a0 = fmaf(v0.w, W2[wb + 3 * H2], a0);
    }
    part[((size_t)blockIdx.z * NROW + r) * H2 + j] = a0;
}

// ---------------- Stage 3: (fused mlp2 epilogue) + logits + CE loss ----------------
__global__ __launch_bounds__(768) void k_loss(const float* __restrict__ part,
                                              const float* __restrict__ b2,
                                              const float* __restrict__ Wc,
                                              const float* __restrict__ bc,
                                              const int* __restrict__ gt,
                                              const float* __restrict__ gt_src,
                                              const float* __restrict__ gt_tgt,
                                              const float* __restrict__ wts,
                                              float* __restrict__ scal) {
    __shared__ float h2s[KK][H2];
    __shared__ float lg[KK][NC];
    __shared__ float rloss[KK], rmask[KK], rlbl[KK], rmatch[KK];

    const int b = blockIdx.x;
    const int t = threadIdx.x;

    // h2 rows = lrelu(b2 + sum of 4 c-slice partials); masked rows produce
    // garbage-but-finite values that are multiplied by mask=0 downstream.
    for (int i = t; i < KK * H2; i += 768) {
        const int row = b * KK + (i >> 9);
        const int jj  = i & 511;
        float s = b2[jj];
#pragma unroll
        for (int p = 0; p < 4; ++p)
            s += part[((size_t)p * NROW + row) * H2 + jj];
        ((float*)h2s)[i] = s > 0.f ? s : NEG * s;
    }
    __syncthreads();

    if (t < KK * NC) {
        const int k = t / NC, j = t % NC;
        float acc = bc[j];
        for (int c = 0; c < H2; ++c) acc = fmaf(h2s[k][c], Wc[(size_t)c * NC + j], acc);
        lg[k][j] = acc;
    }
    __syncthreads();

    if (t < KK) {
        const int k = t;
        float m = -1e30f; int am = 0;
        for (int j = 0; j < NC; ++j) {
            float v = lg[k][j];
            if (v > m) { m = v; am = j; }
        }
        float se = 0.f, celbl = 0.f, lsum = 0.f, lm = -1e30f; int al = 0;
        for (int j = 0; j < NC; ++j) {
            float v = lg[k][j];
            se += expf(v - m);
            float lb = (j < KK) ? gt_src[((size_t)b * KK + k) * KK + j]
                                : gt_tgt[((size_t)b * KK + k) * KK + (j - KK)];
            celbl = fmaf(lb, v, celbl);
            lsum += lb;
            if (lb > lm) { lm = lb; al = j; }
        }
        float lse = m + logf(se);
        float ce = lse * lsum - celbl;
        float mask = (gt[b * KK + k] > 0) ? 1.f : 0.f;
        rloss[k]  = mask * wts[b * KK + k] * ce;
        rmask[k]  = mask;
        rlbl[k]   = mask * lsum;
        rmatch[k] = mask * ((am == al) ? 1.f : 0.f);
    }
    __syncthreads();

    if (t == 0) {
        float n = 0.f, sl = 0.f, ls = 0.f, mt = 0.f;
        for (int k = 0; k < KK; ++k) { n += rmask[k]; sl += rloss[k]; ls += rlbl[k]; mt += rmatch[k]; }
        float sample_loss = sl / fmaxf(n, 1.f);
        bool valid = ls > 0.f;
        atomicAdd(&scal[0], valid ? sample_loss : 0.f);
        atomicAdd(&scal[1], valid ? mt : 0.f);
        atomicAdd(&scal[2], valid ? ls : 0.f);
    }
}

__global__ void k_final(const float* __restrict__ scal, float* __restrict__ out) {
    out[0] = scal[0] / (float)BB;
    out[1] = scal[1] / scal[2] * 100.f;
}

extern "C" void kernel_launch(void* const* d_in, const int* in_sizes, int n_in,
                              void* d_out, int out_size, void* d_ws, size_t ws_size,
                              hipStream_t stream) {
    const float* x      = (const float*)d_in[0];
    const float* cam    = (const float*)d_in[1];
    const int*   gt     = (const int*)d_in[2];
    const float* gt_src = (const float*)d_in[3];
    const float* gt_tgt = (const float*)d_in[4];
    const float* wts    = (const float*)d_in[5];
    const float* W1     = (const float*)d_in[6];
    const float* b1     = (const float*)d_in[7];
    const float* W2     = (const float*)d_in[8];
    const float* b2     = (const float*)d_in[9];
    const float* Wc     = (const float*)d_in[10];
    const float* bc     = (const float*)d_in[11];

    float* ws      = (float*)d_ws;
    float* scal    = ws;                                  // 16 floats
    float* partial = ws + 16;                             // NSL*152*256
    float* h1      = partial + (size_t)NSL * NROW * CC;   // 152*2048
    float* part2   = h1 + (size_t)NROW * H1;              // 4*152*512

    dim3 g1(16 * NSL, BB);                                // 1024 blocks, 4/CU
    k_feat<<<g1, 256, 0, stream>>>(x, cam, gt, partial);
    dim3 g2(H1 / 256, NROW);
    k_mlp1<<<g2, 256, 0, stream>>>(partial, W1, b1, gt, h1, scal);
    dim3 g3(4, NROW, 4);
    k_mlp2p<<<g3, 128, 0, stream>>>(h1, W2, gt, part2);
    k_loss<<<BB, 768, 0, stream>>>(part2, b2, Wc, bc, gt, gt_src, gt_tgt, wts, scal);
    k_final<<<1, 1, 0, stream>>>(scal, (float*)d_out);
}

// Round 19
// 229.691 us; speedup vs baseline: 1.0659x; 1.0659x over previous
//
#include <hip/hip_runtime.h>
#include <stdint.h>

#define BB 8
#define CC 256
#define KK 19
#define HWN 65536
#define H1 2048
#define H2 512
#define NC 38
#define NEG 0.2f
#define NSL 16              // hw slices (R17 best: 2048 blocks, 2 generations)
#define HWS (HWN / NSL)     // 4096 hw per slice
#define HWT 256             // hw per chunk
#define NCH (HWS / HWT)     // 16 chunks per slice
#define CAMF4 (KK * HWT / 4)   // 1216 float4 per cam chunk
#define NROW (BB * KK)      // 152

typedef float nat4 __attribute__((ext_vector_type(4)));   // native vec for nt builtins

// async global->LDS, 16 B per lane (wave-uniform LDS base + lane*16)
__device__ __forceinline__ void gload_lds16(const float4* g, float4* l) {
    __builtin_amdgcn_global_load_lds(
        (const __attribute__((address_space(1))) void*)g,
        (__attribute__((address_space(3))) void*)l, 16, 0, 0);
}

// ---------------- Stage 1: partial[sl][b][k][c] = sum_{hw in slice} cam*x ----------------
// R19 k_feat = EXACT R17 config (best measured: 234 total). R18's NSL=8
// single-generation variant cost +16us (fewer blocks -> less cross-block TLP;
// generation overlap is actually beneficial) and is reverted.
// Keeps: dbuf + async gload_lds staging, nt x-loads, gt-skip.
__global__ __launch_bounds__(256) void k_feat(const float* __restrict__ x,
                                              const float* __restrict__ cam,
                                              const int* __restrict__ gt,
                                              float* __restrict__ partial) {
    __shared__ float cams[2][KK * HWT];      // 2 x 19456 B
    const int b  = blockIdx.y;
    const int cg = blockIdx.x & 15;          // channel group of 16
    const int sl = blockIdx.x >> 4;          // hw slice 0..15
    const int t  = threadIdx.x;
    const int w  = t >> 6;                   // wave 0..3
    const int l  = t & 63;                   // lane
    const int c0 = cg * 16 + w * 4;

    // active-row bitmask (block-uniform -> scalar loads/branches)
    unsigned gtm = 0;
#pragma unroll
    for (int k = 0; k < KK; ++k)
        gtm |= (gt[b * KK + k] > 0) ? (1u << k) : 0u;

    const nat4*  __restrict__ x4  = reinterpret_cast<const nat4*>(x);
    const float4* __restrict__ cb4 = reinterpret_cast<const float4*>(cam) + (size_t)b * KK * (HWN / 4);
    const int slbase = sl * (HWS / 4);

    float acc[KK][4];
#pragma unroll
    for (int k = 0; k < KK; ++k)
#pragma unroll
        for (int c = 0; c < 4; ++c) acc[k][c] = 0.f;

    // stage cam chunk ch into buf via async global->LDS; skip masked rows
    auto stage = [&](int buf, int ch) {
        const int f0 = slbase + ch * (HWT / 4);
#pragma unroll
        for (int j = 0; j < 5; ++j) {
            const int idx = w * 64 + j * 256;            // wave-uniform f4 base
            const int row = idx >> 6;                    // cam row (k)
            if (idx < CAMF4 && ((gtm >> row) & 1)) {     // wave-uniform guard
                gload_lds16(cb4 + (size_t)row * (HWN / 4) + f0 + l,
                            ((float4*)cams[buf]) + idx + l);
            }
        }
    };
    auto loadx = [&](nat4 (&xv)[4], int ch) {
        const int f0 = slbase + ch * (HWT / 4);
#pragma unroll
        for (int c = 0; c < 4; ++c)
            xv[c] = __builtin_nontemporal_load(
                x4 + (size_t)(b * CC + c0 + c) * (HWN / 4) + f0 + l);
    };
    auto consume = [&](int buf, const nat4 (&xv)[4]) {
        const float4* cs = (const float4*)cams[buf];
#pragma unroll
        for (int k = 0; k < KK; ++k) {
            if ((gtm >> k) & 1) {                        // uniform skip
                const float4 cv = cs[k * (HWT / 4) + l]; // conflict-free b128
#pragma unroll
                for (int c = 0; c < 4; ++c)
                    acc[k][c] = fmaf(xv[c].w, cv.w, fmaf(xv[c].z, cv.z,
                                fmaf(xv[c].y, cv.y, fmaf(xv[c].x, cv.x, acc[k][c]))));
            }
        }
    };

    nat4 xa[4], xb[4];
    loadx(xa, 0);
    stage(0, 0);
    __syncthreads();                                     // prologue drain

#pragma unroll 1
    for (int ch = 0; ch < NCH; ch += 2) {
        loadx(xb, ch + 1);                               // prefetch chunk ch+1
        stage(1, ch + 1);
        consume(0, xa);                                  // compute hides latency
        __syncthreads();
        if (ch + 2 < NCH) { loadx(xa, ch + 2); stage(0, ch + 2); }
        consume(1, xb);
        __syncthreads();
    }

    // butterfly wave-reduce each (k,c); lane 0 stores per-slice partial
    // (masked k: acc stayed 0 -> stores 0 -> finite & unused downstream)
#pragma unroll
    for (int k = 0; k < KK; ++k) {
#pragma unroll
        for (int c = 0; c < 4; ++c) {
            float v = acc[k][c];
#pragma unroll
            for (int off = 32; off; off >>= 1) v += __shfl_xor(v, off, 64);
            if (l == 0)
                __builtin_nontemporal_store(v,
                    partial + (size_t)sl * (NROW * CC) +
                    (size_t)(b * KK + k) * CC + c0 + c);
        }
    }
}

// ---------------- Stage 2a (fused reduce): h1 = lrelu(feat @ W1 + b1) ----------------
// grid (8, 152), block 256, ONE row per block; masked rows return early
// (their h1 is never read: k_mlp2p skips them too). Block (0,0) zeroes scal
// BEFORE the mask check.
__global__ __launch_bounds__(256) void k_mlp1(const float* __restrict__ partial,
                                              const float* __restrict__ W1,
                                              const float* __restrict__ b1,
                                              const int* __restrict__ gt,
                                              float* __restrict__ h1,
                                              float* __restrict__ scal) {
    __shared__ float fr[CC];
    const int r = blockIdx.y;                 // 0..151
    const int t = threadIdx.x;
    if (blockIdx.x == 0 && blockIdx.y == 0 && t < 16) scal[t] = 0.f;
    if (gt[r] <= 0) return;                   // masked row: skip entirely

    float s0 = 0.f;
#pragma unroll
    for (int slc = 0; slc < NSL; ++slc)
        s0 += partial[((size_t)slc * NROW + r) * CC + t];
    fr[t] = s0 * (1.0f / (float)HWN);
    __syncthreads();

    const int j = blockIdx.x * 256 + t;
    const float4* f0 = (const float4*)fr;
    float a0 = b1[j];
#pragma unroll 8
    for (int c4 = 0; c4 < CC / 4; ++c4) {
        const float4 v0 = f0[c4];
        const size_t cb = (size_t)(c4 * 4) * H1 + j;
        a0 = fmaf(v0.x, W1[cb], a0);
        a0 = fmaf(v0.y, W1[cb + H1], a0);
        a0 = fmaf(v0.z, W1[cb + 2 * H1], a0);
        a0 = fmaf(v0.w, W1[cb + 3 * H1], a0);
    }
    h1[(size_t)r * H1 + j] = a0 > 0.f ? a0 : NEG * a0;
}

// ---------------- Stage 2b: c-split partial GEMM for h2 (no bias) ----------------
// grid (4 jtile, 152 row, 4 cslice), block 128; masked rows return early
// (their part2 entries stay garbage-but-finite; k_loss multiplies by mask).
__global__ __launch_bounds__(128) void k_mlp2p(const float* __restrict__ h1,
                                               const float* __restrict__ W2,
                                               const int* __restrict__ gt,
                                               float* __restrict__ part) {
    const int r = blockIdx.y;
    if (gt[r] <= 0) return;                   // masked row: skip
    const int j  = blockIdx.x * 128 + threadIdx.x;
    const int cb = blockIdx.z * 512;
    const float4* __restrict__ f0 = reinterpret_cast<const float4*>(h1 + (size_t)r * H1 + cb);

    float a0 = 0.f;
#pragma unroll 8
    for (int c4 = 0; c4 < 128; ++c4) {
        const float4 v0 = f0[c4];
        const size_t wb = (size_t)(cb + c4 * 4) * H2 + j;
        a0 = fmaf(v0.x, W2[wb], a0);
        a0 = fmaf(v0.y, W2[wb + H2], a0);
        a0 = fmaf(v0.z, W2[wb + 2 * H2], a0);
        a0 = fmaf(v0.w, W2[wb + 3 * H2], a0);
    }
    part[((size_t)blockIdx.z * NROW + r) * H2 + j] = a0;
}

// ---------------- Stage 3: (fused mlp2 epilogue) + logits + CE loss ----------------
__global__ __launch_bounds__(768) void k_loss(const float* __restrict__ part,
                                              const float* __restrict__ b2,
                                              const float* __restrict__ Wc,
                                              const float* __restrict__ bc,
                                              const int* __restrict__ gt,
                                              const float* __restrict__ gt_src,
                                              const float* __restrict__ gt_tgt,
                                              const float* __restrict__ wts,
                                              float* __restrict__ scal) {
    __shared__ float h2s[KK][H2];
    __shared__ float lg[KK][NC];
    __shared__ float rloss[KK], rmask[KK], rlbl[KK], rmatch[KK];

    const int b = blockIdx.x;
    const int t = threadIdx.x;

    // h2 rows = lrelu(b2 + sum of 4 c-slice partials); masked rows produce
    // garbage-but-finite values that are multiplied by mask=0 downstream.
    for (int i = t; i < KK * H2; i += 768) {
        const int row = b * KK + (i >> 9);
        const int jj  = i & 511;
        float s = b2[jj];
#pragma unroll
        for (int p = 0; p < 4; ++p)
            s += part[((size_t)p * NROW + row) * H2 + jj];
        ((float*)h2s)[i] = s > 0.f ? s : NEG * s;
    }
    __syncthreads();

    if (t < KK * NC) {
        const int k = t / NC, j = t % NC;
        float acc = bc[j];
        for (int c = 0; c < H2; ++c) acc = fmaf(h2s[k][c], Wc[(size_t)c * NC + j], acc);
        lg[k][j] = acc;
    }
    __syncthreads();

    if (t < KK) {
        const int k = t;
        float m = -1e30f; int am = 0;
        for (int j = 0; j < NC; ++j) {
            float v = lg[k][j];
            if (v > m) { m = v; am = j; }
        }
        float se = 0.f, celbl = 0.f, lsum = 0.f, lm = -1e30f; int al = 0;
        for (int j = 0; j < NC; ++j) {
            float v = lg[k][j];
            se += expf(v - m);
            float lb = (j < KK) ? gt_src[((size_t)b * KK + k) * KK + j]
                                : gt_tgt[((size_t)b * KK + k) * KK + (j - KK)];
            celbl = fmaf(lb, v, celbl);
            lsum += lb;
            if (lb > lm) { lm = lb; al = j; }
        }
        float lse = m + logf(se);
        float ce = lse * lsum - celbl;
        float mask = (gt[b * KK + k] > 0) ? 1.f : 0.f;
        rloss[k]  = mask * wts[b * KK + k] * ce;
        rmask[k]  = mask;
        rlbl[k]   = mask * lsum;
        rmatch[k] = mask * ((am == al) ? 1.f : 0.f);
    }
    __syncthreads();

    if (t == 0) {
        float n = 0.f, sl = 0.f, ls = 0.f, mt = 0.f;
        for (int k = 0; k < KK; ++k) { n += rmask[k]; sl += rloss[k]; ls += rlbl[k]; mt += rmatch[k]; }
        float sample_loss = sl / fmaxf(n, 1.f);
        bool valid = ls > 0.f;
        atomicAdd(&scal[0], valid ? sample_loss : 0.f);
        atomicAdd(&scal[1], valid ? mt : 0.f);
        atomicAdd(&scal[2], valid ? ls : 0.f);
    }
}

__global__ void k_final(const float* __restrict__ scal, float* __restrict__ out) {
    out[0] = scal[0] / (float)BB;
    out[1] = scal[1] / scal[2] * 100.f;
}

extern "C" void kernel_launch(void* const* d_in, const int* in_sizes, int n_in,
                              void* d_out, int out_size, void* d_ws, size_t ws_size,
                              hipStream_t stream) {
    const float* x      = (const float*)d_in[0];
    const float* cam    = (const float*)d_in[1];
    const int*   gt     = (const int*)d_in[2];
    const float* gt_src = (const float*)d_in[3];
    const float* gt_tgt = (const float*)d_in[4];
    const float* wts    = (const float*)d_in[5];
    const float* W1     = (const float*)d_in[6];
    const float* b1     = (const float*)d_in[7];
    const float* W2     = (const float*)d_in[8];
    const float* b2     = (const float*)d_in[9];
    const float* Wc     = (const float*)d_in[10];
    const float* bc     = (const float*)d_in[11];

    float* ws      = (float*)d_ws;
    float* scal    = ws;                                  // 16 floats
    float* partial = ws + 16;                             // NSL*152*256
    float* h1      = partial + (size_t)NSL * NROW * CC;   // 152*2048
    float* part2   = h1 + (size_t)NROW * H1;              // 4*152*512

    dim3 g1(16 * NSL, BB);                                // 2048 blocks
    k_feat<<<g1, 256, 0, stream>>>(x, cam, gt, partial);
    dim3 g2(H1 / 256, NROW);
    k_mlp1<<<g2, 256, 0, stream>>>(partial, W1, b1, gt, h1, scal);
    dim3 g3(4, NROW, 4);
    k_mlp2p<<<g3, 128, 0, stream>>>(h1, W2, gt, part2);
    k_loss<<<BB, 768, 0, stream>>>(part2, b2, Wc, bc, gt, gt_src, gt_tgt, wts, scal);
    k_final<<<1, 1, 0, stream>>>(scal, (float*)d_out);
}